// Round 1
// baseline (25.026 us; speedup 1.0000x reference)
//
#include <hip/hip_runtime.h>

namespace {

constexpr int CH   = 256;   // channels
constexpr int HH   = 256;
constexpr int WW   = 256;
constexpr int NBOX = 100;
constexpr int MAXN = 100;
constexpr int BLOCK = 512;
constexpr int SPLIT = 2;    // blocks per channel for the fill phase

__global__ __launch_bounds__(BLOCK) void comm_kernel(
    const float* __restrict__ boxes,   // [100,8,3]
    const float* __restrict__ scores,  // [100]
    const float* __restrict__ feat,    // [256,256,256]
    float* __restrict__ out)           // [256,256,256]
{
    __shared__ int   sh_idx[MAXN];
    __shared__ float sh_a[MAXN], sh_cx[MAXN], sh_cy[MAXN];
    __shared__ float sh_w00[MAXN], sh_w10[MAXN], sh_w01[MAXN], sh_w11[MAXN];
    __shared__ int   sh_x0[MAXN], sh_x1[MAXN], sh_y0[MAXN], sh_y1[MAXN];
    __shared__ float red[BLOCK / 64][4];
    __shared__ float sS[4];

    const int tid  = threadIdx.x;
    const int c    = blockIdx.x / SPLIT;
    const int half = blockIdx.x % SPLIT;

    // ---- phase 1: nonzero(score > 0, size=100, fill=0), ascending order ----
    if (tid == 0) {
        int cnt = 0;
        for (int i = 0; i < NBOX; ++i)
            if (scores[i] > 0.0f) sh_idx[cnt++] = i;
        for (; cnt < MAXN; ++cnt) sh_idx[cnt] = 0;
    }
    __syncthreads();

    // ---- phase 2: per-box geometry + bilinear taps ----
    if (tid < MAXN) {
        const float* bp = boxes + sh_idx[tid] * 24;
        float lx = bp[0], ly = bp[1];
        float rx = lx,    ry = ly;
        #pragma unroll
        for (int k = 1; k < 8; ++k) {
            float x = bp[k * 3 + 0], y = bp[k * 3 + 1];
            lx = fminf(lx, x); rx = fmaxf(rx, x);
            ly = fminf(ly, y); ry = fmaxf(ry, y);
        }
        const float inv_vox = 1.0f / 160.0f;
        float cx = ((lx + rx) * 0.5f + 128.0f) * inv_vox;
        float cy = ((ly + ry) * 0.5f + 128.0f) * inv_vox;
        float lxn = (lx + 128.0f) * inv_vox, rxn = (rx + 128.0f) * inv_vox;
        float lyn = (ly + 128.0f) * inv_vox, ryn = (ry + 128.0f) * inv_vox;
        float bev = (ryn - lyn) * (rxn - lxn);
        sh_a[tid]  = 1.0f / (2.0f * bev * bev);
        sh_cx[tid] = cx;
        sh_cy[tid] = cy;

        // grid_sample, align_corners=False, zero padding
        float ix = ((cx + 1.0f) * (float)WW - 1.0f) * 0.5f;
        float iy = ((cy + 1.0f) * (float)HH - 1.0f) * 0.5f;
        float x0f = floorf(ix), y0f = floorf(iy);
        float wx1 = ix - x0f, wx0 = 1.0f - wx1;
        float wy1 = iy - y0f, wy0 = 1.0f - wy1;
        int x0 = (int)x0f, y0 = (int)y0f;
        int x1 = x0 + 1,  y1 = y0 + 1;
        bool vx0 = (x0 >= 0) && (x0 < WW), vx1 = (x1 >= 0) && (x1 < WW);
        bool vy0 = (y0 >= 0) && (y0 < HH), vy1 = (y1 >= 0) && (y1 < HH);
        sh_w00[tid] = (vx0 && vy0) ? wx0 * wy0 : 0.0f;
        sh_w10[tid] = (vx1 && vy0) ? wx1 * wy0 : 0.0f;
        sh_w01[tid] = (vx0 && vy1) ? wx0 * wy1 : 0.0f;
        sh_w11[tid] = (vx1 && vy1) ? wx1 * wy1 : 0.0f;
        sh_x0[tid] = min(max(x0, 0), WW - 1);
        sh_x1[tid] = min(max(x1, 0), WW - 1);
        sh_y0[tid] = min(max(y0, 0), HH - 1);
        sh_y1[tid] = min(max(y1, 0), HH - 1);
    }
    __syncthreads();

    // ---- phase 3: per-channel scalars S0..S3 over 100 boxes ----
    float S0 = 0.0f, S1 = 0.0f, S2 = 0.0f, S3 = 0.0f;
    if (tid < MAXN) {
        const float* fc = feat + (size_t)c * (HH * WW);
        int x0 = sh_x0[tid], x1 = sh_x1[tid];
        int y0 = sh_y0[tid], y1 = sh_y1[tid];
        float cpf = fc[y0 * WW + x0] * sh_w00[tid]
                  + fc[y0 * WW + x1] * sh_w10[tid]
                  + fc[y1 * WW + x0] * sh_w01[tid]
                  + fc[y1 * WW + x1] * sh_w11[tid];
        float pa = cpf * sh_a[tid];
        float cx = sh_cx[tid], cy = sh_cy[tid];
        S0 = pa;
        S1 = pa * cx;
        S2 = pa * cy;
        S3 = pa * (cx * cx + cy * cy);
    }
    #pragma unroll
    for (int off = 32; off > 0; off >>= 1) {
        S0 += __shfl_down(S0, off);
        S1 += __shfl_down(S1, off);
        S2 += __shfl_down(S2, off);
        S3 += __shfl_down(S3, off);
    }
    if ((tid & 63) == 0) {
        int wv = tid >> 6;
        red[wv][0] = S0; red[wv][1] = S1; red[wv][2] = S2; red[wv][3] = S3;
    }
    __syncthreads();
    if (tid == 0) {
        float t0 = 0, t1 = 0, t2 = 0, t3 = 0;
        #pragma unroll
        for (int wv = 0; wv < BLOCK / 64; ++wv) {
            t0 += red[wv][0]; t1 += red[wv][1];
            t2 += red[wv][2]; t3 += red[wv][3];
        }
        const float invN = 1.0f / (float)MAXN;
        sS[0] = t0 * invN; sS[1] = t1 * invN;
        sS[2] = t2 * invN; sS[3] = t3 * invN;
    }
    __syncthreads();

    // ---- phase 4: fill this block's half-channel ----
    const float s0 = sS[0], s1 = sS[1], s2 = sS[2], s3 = sS[3];
    float4* oc = (float4*)(out + (size_t)c * (HH * WW));
    const int nvec = (HH * WW) / 4;            // 16384 float4 per channel
    const int per  = nvec / SPLIT;             // per block
    const int beg  = half * per;
    for (int i = beg + tid; i < beg + per; i += BLOCK) {
        int h = i >> 6;                        // 64 float4 per row
        float hf = (float)h;
        float hterm = s0 * (hf * hf) - 2.0f * hf * s2 + s3;
        float wbase = (float)((i & 63) << 2);
        float w0 = wbase, w1 = wbase + 1.0f, w2 = wbase + 2.0f, w3 = wbase + 3.0f;
        float4 v;
        v.x = s0 * (w0 * w0) - 2.0f * w0 * s1 + hterm;
        v.y = s0 * (w1 * w1) - 2.0f * w1 * s1 + hterm;
        v.z = s0 * (w2 * w2) - 2.0f * w2 * s1 + hterm;
        v.w = s0 * (w3 * w3) - 2.0f * w3 * s1 + hterm;
        oc[i] = v;
    }
}

} // namespace

extern "C" void kernel_launch(void* const* d_in, const int* in_sizes, int n_in,
                              void* d_out, int out_size, void* d_ws, size_t ws_size,
                              hipStream_t stream) {
    const float* boxes  = (const float*)d_in[0];  // pred_box_infra [100,8,3]
    const float* scores = (const float*)d_in[1];  // pred_score_infra [100]
    const float* feat   = (const float*)d_in[2];  // infra_features [1,256,256,256]
    float* out = (float*)d_out;                   // [1,256,256,256] f32
    comm_kernel<<<dim3(CH * SPLIT), dim3(BLOCK), 0, stream>>>(boxes, scores, feat, out);
}

// Round 2
// 18.809 us; speedup vs baseline: 1.3306x; 1.3306x over previous
//
#include <hip/hip_runtime.h>

namespace {

constexpr int CH    = 256;   // channels
constexpr int HH    = 256;
constexpr int WW    = 256;
constexpr int NBOX  = 100;
constexpr int MAXN  = 100;
constexpr int BLOCK = 512;
constexpr int SPLIT = 2;     // blocks per channel for the fill phase

__global__ __launch_bounds__(BLOCK) void comm_kernel(
    const float* __restrict__ boxes,   // [100,8,3]
    const float* __restrict__ scores,  // [100]
    const float* __restrict__ feat,    // [256,256,256]
    float* __restrict__ out)           // [256,256,256]
{
    __shared__ float sh_a[NBOX], sh_cx[NBOX], sh_cy[NBOX];
    __shared__ float sh_w00[NBOX], sh_w10[NBOX], sh_w01[NBOX], sh_w11[NBOX];
    __shared__ int   sh_t00[NBOX], sh_t10[NBOX], sh_t01[NBOX], sh_t11[NBOX];
    __shared__ int   sh_idx[MAXN];
    __shared__ int   sh_w0cnt;
    __shared__ float red[BLOCK / 64][4];
    __shared__ float sS[4];

    const int tid  = threadIdx.x;
    const int c    = blockIdx.x / SPLIT;
    const int half = blockIdx.x % SPLIT;

    // ---- compaction predicate (parallel; ascending-order nonzero) ----
    bool p = false;
    if (tid < NBOX) p = scores[tid] > 0.0f;
    unsigned long long mask = __ballot(p);
    if (tid == 0) sh_w0cnt = (int)__popcll(mask);
    if (tid < MAXN) sh_idx[tid] = 0;          // fill_value = 0

    // ---- geometry per ORIGINAL box (runs concurrently with compaction) ----
    if (tid < NBOX) {
        const float* bp = boxes + tid * 24;
        float lx = bp[0], ly = bp[1];
        float rx = lx,    ry = ly;
        #pragma unroll
        for (int k = 1; k < 8; ++k) {
            float x = bp[k * 3 + 0], y = bp[k * 3 + 1];
            lx = fminf(lx, x); rx = fmaxf(rx, x);
            ly = fminf(ly, y); ry = fmaxf(ry, y);
        }
        const float inv_vox = 1.0f / 160.0f;
        float cx = ((lx + rx) * 0.5f + 128.0f) * inv_vox;
        float cy = ((ly + ry) * 0.5f + 128.0f) * inv_vox;
        float lxn = (lx + 128.0f) * inv_vox, rxn = (rx + 128.0f) * inv_vox;
        float lyn = (ly + 128.0f) * inv_vox, ryn = (ry + 128.0f) * inv_vox;
        float bev = (ryn - lyn) * (rxn - lxn);
        sh_a[tid]  = 1.0f / (2.0f * bev * bev);
        sh_cx[tid] = cx;
        sh_cy[tid] = cy;

        // grid_sample taps (align_corners=False, zero padding)
        float ix = ((cx + 1.0f) * (float)WW - 1.0f) * 0.5f;
        float iy = ((cy + 1.0f) * (float)HH - 1.0f) * 0.5f;
        float x0f = floorf(ix), y0f = floorf(iy);
        float wx1 = ix - x0f, wx0 = 1.0f - wx1;
        float wy1 = iy - y0f, wy0 = 1.0f - wy1;
        int x0 = (int)x0f, y0 = (int)y0f;
        int x1 = x0 + 1,  y1 = y0 + 1;
        bool vx0 = (x0 >= 0) && (x0 < WW), vx1 = (x1 >= 0) && (x1 < WW);
        bool vy0 = (y0 >= 0) && (y0 < HH), vy1 = (y1 >= 0) && (y1 < HH);
        sh_w00[tid] = (vx0 && vy0) ? wx0 * wy0 : 0.0f;
        sh_w10[tid] = (vx1 && vy0) ? wx1 * wy0 : 0.0f;
        sh_w01[tid] = (vx0 && vy1) ? wx0 * wy1 : 0.0f;
        sh_w11[tid] = (vx1 && vy1) ? wx1 * wy1 : 0.0f;
        int cx0 = min(max(x0, 0), WW - 1), cx1 = min(max(x1, 0), WW - 1);
        int cy0 = min(max(y0, 0), HH - 1), cy1 = min(max(y1, 0), HH - 1);
        sh_t00[tid] = cy0 * WW + cx0;
        sh_t10[tid] = cy0 * WW + cx1;
        sh_t01[tid] = cy1 * WW + cx0;
        sh_t11[tid] = cy1 * WW + cx1;
    }
    __syncthreads();

    // ---- scatter compaction (prefix by ballot popcount) ----
    if (p) {
        int lane = tid & 63;
        int pos  = (tid >= 64 ? sh_w0cnt : 0)
                 + (int)__popcll(mask & ((1ull << lane) - 1ull));
        sh_idx[pos] = tid;
    }
    __syncthreads();

    // ---- per-channel scalars S0..S3 over the 100 selected boxes ----
    float S0 = 0.0f, S1 = 0.0f, S2 = 0.0f, S3 = 0.0f;
    if (tid < MAXN) {
        const int j = sh_idx[tid];
        const float* fc = feat + (size_t)c * (HH * WW);
        float cpf = fc[sh_t00[j]] * sh_w00[j]
                  + fc[sh_t10[j]] * sh_w10[j]
                  + fc[sh_t01[j]] * sh_w01[j]
                  + fc[sh_t11[j]] * sh_w11[j];
        float pa = cpf * sh_a[j];
        float cx = sh_cx[j], cy = sh_cy[j];
        S0 = pa;
        S1 = pa * cx;
        S2 = pa * cy;
        S3 = pa * (cx * cx + cy * cy);
    }
    #pragma unroll
    for (int off = 32; off > 0; off >>= 1) {
        S0 += __shfl_down(S0, off);
        S1 += __shfl_down(S1, off);
        S2 += __shfl_down(S2, off);
        S3 += __shfl_down(S3, off);
    }
    if ((tid & 63) == 0) {
        int wv = tid >> 6;
        red[wv][0] = S0; red[wv][1] = S1; red[wv][2] = S2; red[wv][3] = S3;
    }
    __syncthreads();
    if (tid == 0) {
        float t0 = 0, t1 = 0, t2 = 0, t3 = 0;
        #pragma unroll
        for (int wv = 0; wv < BLOCK / 64; ++wv) {
            t0 += red[wv][0]; t1 += red[wv][1];
            t2 += red[wv][2]; t3 += red[wv][3];
        }
        const float invN = 1.0f / (float)MAXN;
        sS[0] = t0 * invN; sS[1] = t1 * invN;
        sS[2] = t2 * invN; sS[3] = t3 * invN;
    }
    __syncthreads();

    // ---- fill this block's half-channel: out = s0*(w^2+h^2) - 2w*s1 - 2h*s2 + s3
    const float s0 = sS[0], s1 = sS[1], s2 = sS[2], s3 = sS[3];
    float4* oc = (float4*)(out + (size_t)c * (HH * WW));
    const int nvec = (HH * WW) / 4;            // 16384 float4 per channel
    const int per  = nvec / SPLIT;             // 8192 per block
    const int beg  = half * per;

    // column of this thread is invariant across iterations (BLOCK = 8 rows)
    const float wbase = (float)(((beg + tid) & 63) << 2);
    float4 wq;
    {
        float w0 = wbase, w1 = wbase + 1.0f, w2 = wbase + 2.0f, w3 = wbase + 3.0f;
        wq.x = s0 * (w0 * w0) - 2.0f * w0 * s1;
        wq.y = s0 * (w1 * w1) - 2.0f * w1 * s1;
        wq.z = s0 * (w2 * w2) - 2.0f * w2 * s1;
        wq.w = s0 * (w3 * w3) - 2.0f * w3 * s1;
    }
    for (int i = beg + tid; i < beg + per; i += BLOCK) {
        float hf = (float)(i >> 6);
        float hterm = s0 * (hf * hf) - 2.0f * hf * s2 + s3;
        float4 v;
        v.x = wq.x + hterm;
        v.y = wq.y + hterm;
        v.z = wq.z + hterm;
        v.w = wq.w + hterm;
        oc[i] = v;
    }
}

} // namespace

extern "C" void kernel_launch(void* const* d_in, const int* in_sizes, int n_in,
                              void* d_out, int out_size, void* d_ws, size_t ws_size,
                              hipStream_t stream) {
    const float* boxes  = (const float*)d_in[0];  // pred_box_infra [100,8,3]
    const float* scores = (const float*)d_in[1];  // pred_score_infra [100]
    const float* feat   = (const float*)d_in[2];  // infra_features [1,256,256,256]
    float* out = (float*)d_out;                   // [1,256,256,256] f32
    comm_kernel<<<dim3(CH * SPLIT), dim3(BLOCK), 0, stream>>>(boxes, scores, feat, out);
}